// Round 1
// baseline (848.742 us; speedup 1.0000x reference)
//
#include <hip/hip_runtime.h>
#include <stdint.h>

typedef unsigned int u32;
typedef unsigned short u16;

typedef __attribute__((ext_vector_type(4))) float f32x4;
typedef __attribute__((ext_vector_type(8))) __bf16 bf16x8;

#define NN 100000
#define NE 1600000

typedef __attribute__((address_space(1))) u32 ga_u32;
typedef __attribute__((address_space(3))) u32 ls_u32;

static __device__ __forceinline__ u32 f2bf_bits(float f){
  u32 u = __float_as_uint(f);
  return (u + 0x7fffu + ((u >> 16) & 1u)) >> 16;   // RNE f32->bf16
}
static __device__ __forceinline__ float bf2f(u16 h){ return __uint_as_float(((u32)h) << 16); }

static __device__ __forceinline__ void gload16(const void* g, void* l){
  __builtin_amdgcn_global_load_lds((const ga_u32*)g, (ls_u32*)l, 16, 0, 0);
}

// ---------------- CSR build (counting sort by dst) ----------------
__global__ void k_hist(const int* __restrict__ dst, int* __restrict__ cnt){
  int e = blockIdx.x*256 + threadIdx.x;
  if (e < NE) atomicAdd(&cnt[dst[e]], 1);
}

__global__ void k_scan1(const int* __restrict__ cnt, int* __restrict__ excl, int* __restrict__ bsum){
  __shared__ int s[1024];
  int t = threadIdx.x;
  int i = blockIdx.x*1024 + t;
  int v = (i < NN) ? cnt[i] : 0;
  s[t] = v; __syncthreads();
  int acc = v;
  for (int off = 1; off < 1024; off <<= 1){
    int tmp = (t >= off) ? s[t-off] : 0;
    __syncthreads();
    acc += tmp; s[t] = acc;
    __syncthreads();
  }
  if (i < NN) excl[i] = acc - v;           // block-local exclusive
  if (t == 1023) bsum[blockIdx.x] = acc;   // block total
}

__global__ void k_scan2(int* bsum, int nb){
  if (threadIdx.x == 0 && blockIdx.x == 0){
    int run = 0;
    for (int b = 0; b < nb; b++){ int t = bsum[b]; bsum[b] = run; run += t; }
  }
}

__global__ void k_scan3(const int* __restrict__ cnt, int* __restrict__ row_start,
                        const int* __restrict__ bsum, int* __restrict__ fill_ptr,
                        float* __restrict__ rdeg){
  int i = blockIdx.x*256 + threadIdx.x;
  if (i >= NN) return;
  int rs = row_start[i] + bsum[i >> 10];
  row_start[i] = rs;
  fill_ptr[i]  = rs;
  int c = cnt[i];
  rdeg[i] = 1.0f / (float)(c > 1 ? c : 1);
}

__global__ void k_fill(const int* __restrict__ src, const int* __restrict__ dst,
                       int* __restrict__ fill_ptr, int* __restrict__ ssrc){
  int e = blockIdx.x*256 + threadIdx.x;
  if (e >= NE) return;
  int d = dst[e];
  int pos = atomicAdd(&fill_ptr[d], 1);
  ssrc[pos] = src[e];
}

// ---------------- weight prep: transpose to [N][K] bf16, K-concat [Wl;Wr] ----------------
__global__ void k_wprep(const float* __restrict__ Wl0, const float* __restrict__ Wr0,
                        const float* __restrict__ Wl1, const float* __restrict__ Wr1,
                        const float* __restrict__ Wl2, const float* __restrict__ Wr2,
                        u16* __restrict__ W1t, u16* __restrict__ W2t, u16* __restrict__ W3t){
  int idx = blockIdx.x*256 + threadIdx.x;
  if (idx < 256*256){                       // W1t [256][256]: k<128 Wl0, else Wr0
    int n = idx >> 8, k = idx & 255;
    float v = (k < 128) ? Wl0[k*256 + n] : Wr0[(k-128)*256 + n];
    W1t[idx] = (u16)f2bf_bits(v);
  } else if (idx < 256*256 + 256*512){      // W2t [256][512]: k<256 Wl1, else Wr1
    int j = idx - 256*256;
    int n = j >> 9, k = j & 511;
    float v = (k < 256) ? Wl1[k*256 + n] : Wr1[(k-256)*256 + n];
    W2t[j] = (u16)f2bf_bits(v);
  } else {                                  // W3t [128][256]: n<47 Wl2, 48..94 Wr2, else 0
    int j = idx - (256*256 + 256*512);
    int n = j >> 8, k = j & 255;
    float v = 0.f;
    if (n < 47) v = Wl2[k*47 + n];
    else if (n >= 48 && n < 95) v = Wr2[k*47 + (n-48)];
    W3t[j] = (u16)f2bf_bits(v);
  }
}

__global__ void k_xconv(const float* __restrict__ x, u16* __restrict__ xb){
  int i = blockIdx.x*256 + threadIdx.x;     // 4 floats per thread
  if (i >= NN*128/4) return;
  const float4* xp = (const float4*)x;
  float4 v = xp[i];
  u32 lo = f2bf_bits(v.x) | (f2bf_bits(v.y) << 16);
  u32 hi = f2bf_bits(v.z) | (f2bf_bits(v.w) << 16);
  ((u32*)xb)[2*i]   = lo;
  ((u32*)xb)[2*i+1] = hi;
}

// ---------------- mean aggregation via CSR gather (no atomics) ----------------
template<int F>   // F bf16 features; F/2 threads per node, 256-thread blocks
__global__ void k_agg(const u16* __restrict__ feat, const int* __restrict__ row_start,
                      const int* __restrict__ cnt, const float* __restrict__ rdeg,
                      const int* __restrict__ ssrc, u16* __restrict__ out){
  const int TPN = F/2;
  int i = blockIdx.x * (256/TPN) + threadIdx.x / TPN;
  int t = threadIdx.x % TPN;
  if (i >= NN) return;
  int beg = row_start[i], num = cnt[i];
  float a = 0.f, b = 0.f;
  int j = 0;
  for (; j + 1 < num; j += 2){
    int nb0 = ssrc[beg+j], nb1 = ssrc[beg+j+1];
    u32 p0 = *(const u32*)(feat + (size_t)nb0*F + 2*t);
    u32 p1 = *(const u32*)(feat + (size_t)nb1*F + 2*t);
    a += __uint_as_float(p0 << 16); b += __uint_as_float(p0 & 0xffff0000u);
    a += __uint_as_float(p1 << 16); b += __uint_as_float(p1 & 0xffff0000u);
  }
  if (j < num){
    int nb = ssrc[beg+j];
    u32 p = *(const u32*)(feat + (size_t)nb*F + 2*t);
    a += __uint_as_float(p << 16); b += __uint_as_float(p & 0xffff0000u);
  }
  float r = rdeg[i]; a *= r; b *= r;
  u32 pk = f2bf_bits(a) | (f2bf_bits(b) << 16);
  *(u32*)(out + (size_t)i*F + 2*t) = pk;
}

// ---------------- bf16 MFMA GEMM, 128x128 tile, BK=64, dual-A (K-concat) ----------------
// C[M,N] = act(A@Bt^T + bias), A = [A1 | A2] along K, Bt is [N][K] bf16.
template<bool RELU>
__global__ __launch_bounds__(256) void k_gemm(
    const u16* __restrict__ A1, int K1, const u16* __restrict__ A2, int K2,
    const u16* __restrict__ Bt, const float* __restrict__ bias,
    u16* __restrict__ C, int ldc){
  __shared__ u16 As[128*64];
  __shared__ u16 Bs[128*64];
  const int M = NN;
  const int K = K1 + K2;
  const int gm = (M + 127) >> 7;
  int bm = blockIdx.x % gm, bn = blockIdx.x / gm;
  int tid = threadIdx.x;
  int lane = tid & 63, w = tid >> 6;
  int wm = w >> 1, wn = w & 1;               // 4 waves = 2x2, 64x64 each
  int lr = lane & 15, l4 = lane >> 4;
  f32x4 acc[4][4] = {};
  const int nk = K >> 6;
  for (int kstep = 0; kstep < nk; kstep++){
    __syncthreads();                          // previous tile fully consumed
    #pragma unroll
    for (int q = 0; q < 4; q++){
      int L = q*4096 + tid*16;                // linear LDS dest (gload_lds requirement)
      int row = L >> 7;                       // 128B per row (64 bf16)
      int c16 = ((L >> 4) & 7) ^ (row & 7);   // inverse-swizzled SOURCE (G4/m173 pattern)
      int gk = (kstep << 6) + (c16 << 3);
      int grow = bm*128 + row; if (grow >= M) grow = M - 1;   // clamp tail rows
      const u16* ga = (gk < K1) ? (A1 + (size_t)grow*K1 + gk)
                                : (A2 + (size_t)grow*K2 + (gk - K1));
      gload16(ga, (char*)As + L);
      int gcol = bn*128 + row;                // N padded to 128-multiples
      gload16(Bt + (size_t)gcol*K + gk, (char*)Bs + L);
    }
    __syncthreads();                          // compiler drains vmcnt before barrier
    #pragma unroll
    for (int kk = 0; kk < 2; kk++){
      bf16x8 af[4], bf[4];
      #pragma unroll
      for (int fm = 0; fm < 4; fm++){
        int row = wm*64 + fm*16 + lr;
        int c16 = (kk << 2) + l4;
        af[fm] = *(const bf16x8*)((const char*)As + row*128 + ((c16 ^ (row&7)) << 4));
      }
      #pragma unroll
      for (int fn = 0; fn < 4; fn++){
        int row = wn*64 + fn*16 + lr;
        int c16 = (kk << 2) + l4;
        bf[fn] = *(const bf16x8*)((const char*)Bs + row*128 + ((c16 ^ (row&7)) << 4));
      }
      #pragma unroll
      for (int fm = 0; fm < 4; fm++)
        #pragma unroll
        for (int fn = 0; fn < 4; fn++)
          acc[fm][fn] = __builtin_amdgcn_mfma_f32_16x16x32_bf16(af[fm], bf[fn], acc[fm][fn], 0, 0, 0);
    }
  }
  // epilogue: C/D map col=lane&15, row=(lane>>4)*4+q  [m89-verified]
  #pragma unroll
  for (int fn = 0; fn < 4; fn++){
    int col = bn*128 + wn*64 + fn*16 + lr;
    float bv = bias ? bias[col] : 0.f;
    #pragma unroll
    for (int fm = 0; fm < 4; fm++){
      #pragma unroll
      for (int q = 0; q < 4; q++){
        int rowg = bm*128 + wm*64 + fm*16 + l4*4 + q;
        if (rowg < M){
          float v = acc[fm][fn][q] + bv;
          if (RELU) v = fmaxf(v, 0.f);
          C[(size_t)rowg*ldc + col] = (u16)f2bf_bits(v);
        }
      }
    }
  }
}

// ---------------- layer3 tail: agg(t) + root + b2 + log_softmax, 1 wave/node ----------------
__global__ void k_final(const u16* __restrict__ G, const int* __restrict__ row_start,
                        const int* __restrict__ cnt, const float* __restrict__ rdeg,
                        const int* __restrict__ ssrc, const float* __restrict__ b2,
                        float* __restrict__ out){
  int i = blockIdx.x*4 + (threadIdx.x >> 6);
  int f = threadIdx.x & 63;
  if (i >= NN) return;
  bool valid = f < 47;
  int beg = row_start[i], num = cnt[i];
  float s = 0.f;
  int j = 0;
  for (; j + 1 < num; j += 2){
    int nb0 = ssrc[beg+j], nb1 = ssrc[beg+j+1];
    s += bf2f(G[(size_t)nb0*128 + f]);
    s += bf2f(G[(size_t)nb1*128 + f]);
  }
  if (j < num){
    int nb = ssrc[beg+j];
    s += bf2f(G[(size_t)nb*128 + f]);
  }
  float root = bf2f(G[(size_t)i*128 + 48 + f]);   // cols 48..94 = h2@Wr2
  float v = -__builtin_inff();
  if (valid) v = s * rdeg[i] + root + b2[f];
  float m = v;
  #pragma unroll
  for (int o = 32; o > 0; o >>= 1) m = fmaxf(m, __shfl_xor(m, o, 64));
  float e = valid ? expf(v - m) : 0.f;
  float sum = e;
  #pragma unroll
  for (int o = 32; o > 0; o >>= 1) sum += __shfl_xor(sum, o, 64);
  if (valid) out[(size_t)i*47 + f] = v - m - logf(sum);
}

// ---------------- launcher ----------------
extern "C" void kernel_launch(void* const* d_in, const int* in_sizes, int n_in,
                              void* d_out, int out_size, void* d_ws, size_t ws_size,
                              hipStream_t stream){
  const float* x   = (const float*)d_in[0];
  const int*   src = (const int*)d_in[1];
  const int*   dst = (const int*)d_in[2];
  const float* Wl0 = (const float*)d_in[3];
  const float* Wr0 = (const float*)d_in[4];
  const float* b0  = (const float*)d_in[5];
  const float* Wl1 = (const float*)d_in[6];
  const float* Wr1 = (const float*)d_in[7];
  const float* b1  = (const float*)d_in[8];
  const float* Wl2 = (const float*)d_in[9];
  const float* Wr2 = (const float*)d_in[10];
  const float* b2  = (const float*)d_in[11];
  float* out = (float*)d_out;

  char* p = (char*)d_ws;
  size_t off = 0;
  auto alloc = [&](size_t bytes)->char*{
    char* r = p + off; off += (bytes + 511) & ~((size_t)511); return r;
  };
  int*   cnt       = (int*)  alloc((size_t)NN*4);
  int*   row_start = (int*)  alloc((size_t)NN*4);
  int*   fill_ptr  = (int*)  alloc((size_t)NN*4);
  float* rdeg      = (float*)alloc((size_t)NN*4);
  int*   bsum      = (int*)  alloc(512);
  int*   ssrc      = (int*)  alloc((size_t)NE*4);
  u16*   W1t       = (u16*)  alloc((size_t)256*256*2);
  u16*   W2t       = (u16*)  alloc((size_t)256*512*2);
  u16*   W3t       = (u16*)  alloc((size_t)128*256*2);
  u16*   xb        = (u16*)  alloc((size_t)NN*128*2);  // reused as G after GEMM1
  u16*   agg1      = (u16*)  alloc((size_t)NN*128*2);
  u16*   h1        = (u16*)  alloc((size_t)NN*256*2);
  u16*   agg2      = (u16*)  alloc((size_t)NN*256*2);
  u16*   h2        = (u16*)  alloc((size_t)NN*256*2);
  u16*   G = xb;
  // total ws use: ~213 MB

  const int nb_scan = (NN + 1023) / 1024;

  hipMemsetAsync(cnt, 0, (size_t)NN*4, stream);
  k_hist <<<NE/256, 256, 0, stream>>>(dst, cnt);
  k_scan1<<<nb_scan, 1024, 0, stream>>>(cnt, row_start, bsum);
  k_scan2<<<1, 64, 0, stream>>>(bsum, nb_scan);
  k_scan3<<<(NN+255)/256, 256, 0, stream>>>(cnt, row_start, bsum, fill_ptr, rdeg);
  k_fill <<<NE/256, 256, 0, stream>>>(src, dst, fill_ptr, ssrc);
  k_wprep<<<(256*256 + 256*512 + 128*256)/256, 256, 0, stream>>>(Wl0,Wr0,Wl1,Wr1,Wl2,Wr2,W1t,W2t,W3t);
  k_xconv<<<(NN*128/4 + 255)/256, 256, 0, stream>>>(x, xb);

  // layer 1: agg(x) 128-dim, then h1 = relu([agg1|x] @ W1t + b0)
  k_agg<128><<<(NN+3)/4, 256, 0, stream>>>(xb, row_start, cnt, rdeg, ssrc, agg1);
  k_gemm<true><<<782*2, 256, 0, stream>>>(agg1, 128, xb, 128, W1t, b0, h1, 256);

  // layer 2: agg(h1) 256-dim, then h2 = relu([agg2|h1] @ W2t + b1)
  k_agg<256><<<(NN+1)/2, 256, 0, stream>>>(h1, row_start, cnt, rdeg, ssrc, agg2);
  k_gemm<true><<<782*2, 256, 0, stream>>>(agg2, 256, h1, 256, W2t, b1, h2, 256);

  // layer 3: G = h2 @ [Wl2|Wr2] (N padded to 128), then agg(t)+root+b2+log_softmax
  k_gemm<false><<<782, 256, 0, stream>>>(h2, 256, h2, 0, W3t, nullptr, G, 128);
  k_final<<<(NN+3)/4, 256, 0, stream>>>(G, row_start, cnt, rdeg, ssrc, b2, out);
}

// Round 5
// 709.667 us; speedup vs baseline: 1.1960x; 1.1960x over previous
//
#include <hip/hip_runtime.h>
#include <stdint.h>

typedef unsigned int u32;
typedef unsigned short u16;

typedef __attribute__((ext_vector_type(4))) float f32x4;
typedef __attribute__((ext_vector_type(8))) __bf16 bf16x8;

#define NN 100000
#define NE 1600000

typedef __attribute__((address_space(1))) u32 ga_u32;
typedef __attribute__((address_space(3))) u32 ls_u32;

static __device__ __forceinline__ u32 f2bf_bits(float f){
  u32 u = __float_as_uint(f);
  return (u + 0x7fffu + ((u >> 16) & 1u)) >> 16;   // RNE f32->bf16
}
static __device__ __forceinline__ float bf2f(u16 h){ return __uint_as_float(((u32)h) << 16); }

static __device__ __forceinline__ void gload16(const void* g, void* l){
  __builtin_amdgcn_global_load_lds((const ga_u32*)g, (ls_u32*)l, 16, 0, 0);
}

// ---------------- CSR build (counting sort by dst) ----------------
__global__ void k_hist(const int* __restrict__ dst, int* __restrict__ cnt){
  int e = blockIdx.x*256 + threadIdx.x;
  if (e < NE) atomicAdd(&cnt[dst[e]], 1);
}

__global__ void k_scan1(const int* __restrict__ cnt, int* __restrict__ excl, int* __restrict__ bsum){
  __shared__ int s[1024];
  int t = threadIdx.x;
  int i = blockIdx.x*1024 + t;
  int v = (i < NN) ? cnt[i] : 0;
  s[t] = v; __syncthreads();
  int acc = v;
  for (int off = 1; off < 1024; off <<= 1){
    int tmp = (t >= off) ? s[t-off] : 0;
    __syncthreads();
    acc += tmp; s[t] = acc;
    __syncthreads();
  }
  if (i < NN) excl[i] = acc - v;           // block-local exclusive
  if (t == 1023) bsum[blockIdx.x] = acc;   // block total
}

__global__ void k_scan2(int* bsum, int nb){
  if (threadIdx.x == 0 && blockIdx.x == 0){
    int run = 0;
    for (int b = 0; b < nb; b++){ int t = bsum[b]; bsum[b] = run; run += t; }
  }
}

__global__ void k_scan3(const int* __restrict__ cnt, int* __restrict__ row_start,
                        const int* __restrict__ bsum, int* __restrict__ fill_ptr,
                        float* __restrict__ rdeg){
  int i = blockIdx.x*256 + threadIdx.x;
  if (i >= NN) return;
  int rs = row_start[i] + bsum[i >> 10];
  row_start[i] = rs;
  fill_ptr[i]  = rs;
  int c = cnt[i];
  rdeg[i] = 1.0f / (float)(c > 1 ? c : 1);
}

__global__ void k_fill(const int* __restrict__ src, const int* __restrict__ dst,
                       int* __restrict__ fill_ptr, int* __restrict__ ssrc){
  int e = blockIdx.x*256 + threadIdx.x;
  if (e >= NE) return;
  int d = dst[e];
  int pos = atomicAdd(&fill_ptr[d], 1);
  ssrc[pos] = src[e];
}

// ---------------- weight prep: transpose to [N][K] bf16, K-concat [Wl;Wr] ----------------
__global__ void k_wprep(const float* __restrict__ Wl0, const float* __restrict__ Wr0,
                        const float* __restrict__ Wl1, const float* __restrict__ Wr1,
                        const float* __restrict__ Wl2, const float* __restrict__ Wr2,
                        u16* __restrict__ W1t, u16* __restrict__ W2t, u16* __restrict__ W3t){
  int idx = blockIdx.x*256 + threadIdx.x;
  if (idx < 256*256){                       // W1t [256][256]: k<128 Wl0, else Wr0
    int n = idx >> 8, k = idx & 255;
    float v = (k < 128) ? Wl0[k*256 + n] : Wr0[(k-128)*256 + n];
    W1t[idx] = (u16)f2bf_bits(v);
  } else if (idx < 256*256 + 256*512){      // W2t [256][512]: k<256 Wl1, else Wr1
    int j = idx - 256*256;
    int n = j >> 9, k = j & 511;
    float v = (k < 256) ? Wl1[k*256 + n] : Wr1[(k-256)*256 + n];
    W2t[j] = (u16)f2bf_bits(v);
  } else {                                  // W3t [128][256]: n<47 Wl2, 48..94 Wr2, else 0
    int j = idx - (256*256 + 256*512);
    int n = j >> 8, k = j & 255;
    float v = 0.f;
    if (n < 47) v = Wl2[k*47 + n];
    else if (n >= 48 && n < 95) v = Wr2[k*47 + (n-48)];
    W3t[j] = (u16)f2bf_bits(v);
  }
}

__global__ void k_xconv(const float* __restrict__ x, u16* __restrict__ xb){
  int i = blockIdx.x*256 + threadIdx.x;     // 4 floats per thread
  if (i >= NN*128/4) return;
  const float4* xp = (const float4*)x;
  float4 v = xp[i];
  u32 lo = f2bf_bits(v.x) | (f2bf_bits(v.y) << 16);
  u32 hi = f2bf_bits(v.z) | (f2bf_bits(v.w) << 16);
  ((u32*)xb)[2*i]   = lo;
  ((u32*)xb)[2*i+1] = hi;
}

// ---------------- mean aggregation: 1 wave/node, wide loads, deep unroll ----------------
// EPL = F/64 bf16 per lane (2 -> dword, 4 -> dwordx2). UN-deep neighbor unroll.
template<int F, int UN>
__global__ __launch_bounds__(256) void k_agg(const u16* __restrict__ feat,
    const int* __restrict__ row_start, const int* __restrict__ cnt,
    const float* __restrict__ rdeg, const int* __restrict__ ssrc,
    u16* __restrict__ out){
  constexpr int EPL = F/64;
  int i = blockIdx.x*4 + (threadIdx.x >> 6);
  if (i >= NN) return;
  int lane = threadIdx.x & 63;
  const u16* fp = feat + (size_t)lane*EPL;
  int beg = row_start[i], num = cnt[i];
  float a0=0.f, b0=0.f, a1=0.f, b1=0.f;
  int j = 0;
  for (; j + UN <= num; j += UN){
    u32 w0[UN], w1[UN];
    #pragma unroll
    for (int u = 0; u < UN; u++){
      const u16* q = fp + (size_t)ssrc[beg+j+u]*F;
      if constexpr (EPL == 4){ uint2 t2 = *(const uint2*)q; w0[u] = t2.x; w1[u] = t2.y; }
      else                   { w0[u] = *(const u32*)q; }
    }
    #pragma unroll
    for (int u = 0; u < UN; u++){
      a0 += __uint_as_float(w0[u] << 16); b0 += __uint_as_float(w0[u] & 0xffff0000u);
      if constexpr (EPL == 4){
        a1 += __uint_as_float(w1[u] << 16); b1 += __uint_as_float(w1[u] & 0xffff0000u);
      }
    }
  }
  for (; j + 2 <= num; j += 2){              // 2-deep tail (LOOP — handles any remainder)
    u32 w0[2], w1[2];
    #pragma unroll
    for (int u = 0; u < 2; u++){
      const u16* q = fp + (size_t)ssrc[beg+j+u]*F;
      if constexpr (EPL == 4){ uint2 t2 = *(const uint2*)q; w0[u] = t2.x; w1[u] = t2.y; }
      else                   { w0[u] = *(const u32*)q; }
    }
    #pragma unroll
    for (int u = 0; u < 2; u++){
      a0 += __uint_as_float(w0[u] << 16); b0 += __uint_as_float(w0[u] & 0xffff0000u);
      if constexpr (EPL == 4){
        a1 += __uint_as_float(w1[u] << 16); b1 += __uint_as_float(w1[u] & 0xffff0000u);
      }
    }
  }
  if (j < num){                              // 1 tail
    const u16* q = fp + (size_t)ssrc[beg+j]*F;
    if constexpr (EPL == 4){
      uint2 t2 = *(const uint2*)q;
      a0 += __uint_as_float(t2.x << 16); b0 += __uint_as_float(t2.x & 0xffff0000u);
      a1 += __uint_as_float(t2.y << 16); b1 += __uint_as_float(t2.y & 0xffff0000u);
    } else {
      u32 p = *(const u32*)q;
      a0 += __uint_as_float(p << 16); b0 += __uint_as_float(p & 0xffff0000u);
    }
  }
  float r = rdeg[i];
  if constexpr (EPL == 4){
    uint2 pk;
    pk.x = f2bf_bits(a0*r) | (f2bf_bits(b0*r) << 16);
    pk.y = f2bf_bits(a1*r) | (f2bf_bits(b1*r) << 16);
    *(uint2*)(out + (size_t)i*F + lane*4) = pk;
  } else {
    *(u32*)(out + (size_t)i*F + lane*2) = f2bf_bits(a0*r) | (f2bf_bits(b0*r) << 16);
  }
}

// ---------------- bf16 MFMA GEMM, 128x128 tile, BK=64, dual-A (K-concat) ----------------
template<bool RELU>
__global__ __launch_bounds__(256) void k_gemm(
    const u16* __restrict__ A1, int K1, const u16* __restrict__ A2, int K2,
    const u16* __restrict__ Bt, const float* __restrict__ bias,
    u16* __restrict__ C, int ldc){
  __shared__ u16 As[128*64];
  __shared__ u16 Bs[128*64];
  const int M = NN;
  const int K = K1 + K2;
  const int gm = (M + 127) >> 7;
  int bm = blockIdx.x % gm, bn = blockIdx.x / gm;
  int tid = threadIdx.x;
  int lane = tid & 63, w = tid >> 6;
  int wm = w >> 1, wn = w & 1;               // 4 waves = 2x2, 64x64 each
  int lr = lane & 15, l4 = lane >> 4;
  f32x4 acc[4][4] = {};
  const int nk = K >> 6;
  for (int kstep = 0; kstep < nk; kstep++){
    __syncthreads();
    #pragma unroll
    for (int q = 0; q < 4; q++){
      int L = q*4096 + tid*16;                // linear LDS dest (gload_lds requirement)
      int row = L >> 7;                       // 128B per row (64 bf16)
      int c16 = ((L >> 4) & 7) ^ (row & 7);   // inverse-swizzled SOURCE
      int gk = (kstep << 6) + (c16 << 3);
      int grow = bm*128 + row; if (grow >= M) grow = M - 1;
      const u16* ga = (gk < K1) ? (A1 + (size_t)grow*K1 + gk)
                                : (A2 + (size_t)grow*K2 + (gk - K1));
      gload16(ga, (char*)As + L);
      int gcol = bn*128 + row;
      gload16(Bt + (size_t)gcol*K + gk, (char*)Bs + L);
    }
    __syncthreads();
    #pragma unroll
    for (int kk = 0; kk < 2; kk++){
      bf16x8 af[4], bf[4];
      #pragma unroll
      for (int fm = 0; fm < 4; fm++){
        int row = wm*64 + fm*16 + lr;
        int c16 = (kk << 2) + l4;
        af[fm] = *(const bf16x8*)((const char*)As + row*128 + ((c16 ^ (row&7)) << 4));
      }
      #pragma unroll
      for (int fn = 0; fn < 4; fn++){
        int row = wn*64 + fn*16 + lr;
        int c16 = (kk << 2) + l4;
        bf[fn] = *(const bf16x8*)((const char*)Bs + row*128 + ((c16 ^ (row&7)) << 4));
      }
      #pragma unroll
      for (int fm = 0; fm < 4; fm++)
        #pragma unroll
        for (int fn = 0; fn < 4; fn++)
          acc[fm][fn] = __builtin_amdgcn_mfma_f32_16x16x32_bf16(af[fm], bf[fn], acc[fm][fn], 0, 0, 0);
    }
  }
  #pragma unroll
  for (int fn = 0; fn < 4; fn++){
    int col = bn*128 + wn*64 + fn*16 + lr;
    float bv = bias ? bias[col] : 0.f;
    #pragma unroll
    for (int fm = 0; fm < 4; fm++){
      #pragma unroll
      for (int q = 0; q < 4; q++){
        int rowg = bm*128 + wm*64 + fm*16 + l4*4 + q;
        if (rowg < M){
          float v = acc[fm][fn][q] + bv;
          if (RELU) v = fmaxf(v, 0.f);
          C[(size_t)rowg*ldc + col] = (u16)f2bf_bits(v);
        }
      }
    }
  }
}

// ---------------- layer3 tail: agg(t) + root + b2 + log_softmax ----------------
// half-wave (32 lanes) per node; lane t owns features 2t, 2t+1 (valid < 47)
__global__ __launch_bounds__(256) void k_final(const u16* __restrict__ G,
    const int* __restrict__ row_start, const int* __restrict__ cnt,
    const float* __restrict__ rdeg, const int* __restrict__ ssrc,
    const float* __restrict__ b2, float* __restrict__ out){
  int i = blockIdx.x*8 + (threadIdx.x >> 5);
  if (i >= NN) return;
  int t = threadIdx.x & 31;
  int beg = row_start[i], num = cnt[i];
  const u16* gp = G + 2*t;                   // cols 2t, 2t+1 (<=63, in-bounds)
  float a = 0.f, b = 0.f;
  int j = 0;
  for (; j + 4 <= num; j += 4){
    u32 w[4];
    #pragma unroll
    for (int u = 0; u < 4; u++) w[u] = *(const u32*)(gp + (size_t)ssrc[beg+j+u]*128);
    #pragma unroll
    for (int u = 0; u < 4; u++){ a += __uint_as_float(w[u] << 16); b += __uint_as_float(w[u] & 0xffff0000u); }
  }
  for (; j < num; j++){
    u32 w = *(const u32*)(gp + (size_t)ssrc[beg+j]*128);
    a += __uint_as_float(w << 16); b += __uint_as_float(w & 0xffff0000u);
  }
  float r = rdeg[i];
  u32 rw = *(const u32*)(G + (size_t)i*128 + 48 + 2*t);  // root cols 48+2t, 49+2t
  int f0 = 2*t, f1 = 2*t + 1;
  float va = (f0 < 47) ? a*r + __uint_as_float(rw << 16)          + b2[f0] : -3.0e38f;
  float vb = (f1 < 47) ? b*r + __uint_as_float(rw & 0xffff0000u)  + b2[f1] : -3.0e38f;
  float m = fmaxf(va, vb);
  #pragma unroll
  for (int o = 16; o > 0; o >>= 1) m = fmaxf(m, __shfl_xor(m, o, 32));
  float e = 0.f;
  if (f0 < 47) e += expf(va - m);
  if (f1 < 47) e += expf(vb - m);
  float s = e;
  #pragma unroll
  for (int o = 16; o > 0; o >>= 1) s += __shfl_xor(s, o, 32);
  float ls = logf(s);
  if (f0 < 47) out[(size_t)i*47 + f0] = va - m - ls;
  if (f1 < 47) out[(size_t)i*47 + f1] = vb - m - ls;
}

// ---------------- launcher ----------------
extern "C" void kernel_launch(void* const* d_in, const int* in_sizes, int n_in,
                              void* d_out, int out_size, void* d_ws, size_t ws_size,
                              hipStream_t stream){
  const float* x   = (const float*)d_in[0];
  const int*   src = (const int*)d_in[1];
  const int*   dst = (const int*)d_in[2];
  const float* Wl0 = (const float*)d_in[3];
  const float* Wr0 = (const float*)d_in[4];
  const float* b0  = (const float*)d_in[5];
  const float* Wl1 = (const float*)d_in[6];
  const float* Wr1 = (const float*)d_in[7];
  const float* b1  = (const float*)d_in[8];
  const float* Wl2 = (const float*)d_in[9];
  const float* Wr2 = (const float*)d_in[10];
  const float* b2  = (const float*)d_in[11];
  float* out = (float*)d_out;

  char* p = (char*)d_ws;
  size_t off = 0;
  auto alloc = [&](size_t bytes)->char*{
    char* r = p + off; off += (bytes + 511) & ~((size_t)511); return r;
  };
  int*   cnt       = (int*)  alloc((size_t)NN*4);
  int*   row_start = (int*)  alloc((size_t)NN*4);
  int*   fill_ptr  = (int*)  alloc((size_t)NN*4);
  float* rdeg      = (float*)alloc((size_t)NN*4);
  int*   bsum      = (int*)  alloc(512);
  int*   ssrc      = (int*)  alloc((size_t)NE*4);
  u16*   W1t       = (u16*)  alloc((size_t)256*256*2);
  u16*   W2t       = (u16*)  alloc((size_t)256*512*2);
  u16*   W3t       = (u16*)  alloc((size_t)128*256*2);
  u16*   xb        = (u16*)  alloc((size_t)NN*128*2);  // reused as G after GEMM3
  u16*   agg1      = (u16*)  alloc((size_t)NN*128*2);
  u16*   h1        = (u16*)  alloc((size_t)NN*256*2);
  u16*   agg2      = (u16*)  alloc((size_t)NN*256*2);
  u16*   h2        = (u16*)  alloc((size_t)NN*256*2);
  u16*   G = xb;

  const int nb_scan = (NN + 1023) / 1024;

  hipMemsetAsync(cnt, 0, (size_t)NN*4, stream);
  k_hist <<<NE/256, 256, 0, stream>>>(dst, cnt);
  k_scan1<<<nb_scan, 1024, 0, stream>>>(cnt, row_start, bsum);
  k_scan2<<<1, 64, 0, stream>>>(bsum, nb_scan);
  k_scan3<<<(NN+255)/256, 256, 0, stream>>>(cnt, row_start, bsum, fill_ptr, rdeg);
  k_fill <<<NE/256, 256, 0, stream>>>(src, dst, fill_ptr, ssrc);
  k_wprep<<<(256*256 + 256*512 + 128*256)/256, 256, 0, stream>>>(Wl0,Wr0,Wl1,Wr1,Wl2,Wr2,W1t,W2t,W3t);
  k_xconv<<<(NN*128/4 + 255)/256, 256, 0, stream>>>(x, xb);

  // layer 1: agg(x) 128-dim, then h1 = relu([agg1|x] @ W1t + b0)
  k_agg<128,8><<<(NN+3)/4, 256, 0, stream>>>(xb, row_start, cnt, rdeg, ssrc, agg1);
  k_gemm<true><<<782*2, 256, 0, stream>>>(agg1, 128, xb, 128, W1t, b0, h1, 256);

  // layer 2: agg(h1) 256-dim, then h2 = relu([agg2|h1] @ W2t + b1)
  k_agg<256,4><<<(NN+3)/4, 256, 0, stream>>>(h1, row_start, cnt, rdeg, ssrc, agg2);
  k_gemm<true><<<782*2, 256, 0, stream>>>(agg2, 256, h1, 256, W2t, b1, h2, 256);

  // layer 3: G = h2 @ [Wl2|Wr2] (N padded to 128), then agg(t)+root+b2+log_softmax
  k_gemm<false><<<782, 256, 0, stream>>>(h2, 256, h2, 0, W3t, nullptr, G, 128);
  k_final<<<(NN+7)/8, 256, 0, stream>>>(G, row_start, cnt, rdeg, ssrc, b2, out);
}

// Round 6
// 669.159 us; speedup vs baseline: 1.2684x; 1.0605x over previous
//
#include <hip/hip_runtime.h>
#include <stdint.h>

typedef unsigned int u32;
typedef unsigned short u16;

typedef __attribute__((ext_vector_type(4))) float f32x4;
typedef __attribute__((ext_vector_type(8))) __bf16 bf16x8;

#define NN 100000
#define NE 1600000
#define NSLICE 8
#define SLICE_NODES 12500   // NN / NSLICE exactly

typedef __attribute__((address_space(1))) u32 ga_u32;
typedef __attribute__((address_space(3))) u32 ls_u32;

static __device__ __forceinline__ u32 f2bf_bits(float f){
  u32 u = __float_as_uint(f);
  return (u + 0x7fffu + ((u >> 16) & 1u)) >> 16;   // RNE f32->bf16
}
static __device__ __forceinline__ float bf2f(u16 h){ return __uint_as_float(((u32)h) << 16); }

static __device__ __forceinline__ void gload16(const void* g, void* l){
  __builtin_amdgcn_global_load_lds((const ga_u32*)g, (ls_u32*)l, 16, 0, 0);
}

// ---------------- CSR build (counting sort by dst) ----------------
__global__ void k_hist(const int* __restrict__ dst, int* __restrict__ cnt){
  int e = blockIdx.x*256 + threadIdx.x;
  if (e < NE) atomicAdd(&cnt[dst[e]], 1);
}

__global__ void k_scan1(const int* __restrict__ cnt, int* __restrict__ excl, int* __restrict__ bsum){
  __shared__ int s[1024];
  int t = threadIdx.x;
  int i = blockIdx.x*1024 + t;
  int v = (i < NN) ? cnt[i] : 0;
  s[t] = v; __syncthreads();
  int acc = v;
  for (int off = 1; off < 1024; off <<= 1){
    int tmp = (t >= off) ? s[t-off] : 0;
    __syncthreads();
    acc += tmp; s[t] = acc;
    __syncthreads();
  }
  if (i < NN) excl[i] = acc - v;           // block-local exclusive
  if (t == 1023) bsum[blockIdx.x] = acc;   // block total
}

__global__ void k_scan2(int* bsum, int nb){
  if (threadIdx.x == 0 && blockIdx.x == 0){
    int run = 0;
    for (int b = 0; b < nb; b++){ int t = bsum[b]; bsum[b] = run; run += t; }
  }
}

__global__ void k_scan3(const int* __restrict__ cnt, int* __restrict__ row_start,
                        const int* __restrict__ bsum, int* __restrict__ fill_ptr,
                        float* __restrict__ rdeg){
  int i = blockIdx.x*256 + threadIdx.x;
  if (i >= NN) return;
  int rs = row_start[i] + bsum[i >> 10];
  row_start[i] = rs;
  fill_ptr[i]  = rs;
  int c = cnt[i];
  rdeg[i] = 1.0f / (float)(c > 1 ? c : 1);
}

// dst-sliced fill: slice = blockIdx&7 handles dst in [slice*12500,(slice+1)*12500).
// With round-robin block->XCD dispatch each slice's ssrc window + counters stay in
// ONE XCD's L2 -> single-writer 64B lines, full-line writebacks (was 105 MB partial
// writes from 8 non-coherent L2s). Correct regardless of actual XCD mapping.
__global__ __launch_bounds__(256) void k_fill(const int* __restrict__ src,
    const int* __restrict__ dst, int* __restrict__ fill_ptr, int* __restrict__ ssrc){
  int slice = blockIdx.x & 7;
  int bin   = blockIdx.x >> 3;
  int nbin  = gridDim.x >> 3;
  int lo = slice * SLICE_NODES;
  int hi = lo + SLICE_NODES;
  for (int e = bin*256 + threadIdx.x; e < NE; e += nbin*256){
    int d = dst[e];
    if (d >= lo && d < hi){
      int pos = atomicAdd(&fill_ptr[d], 1);
      ssrc[pos] = src[e];
    }
  }
}

// ---------------- weight prep: transpose to [N][K] bf16, K-concat [Wl;Wr] ----------------
__global__ void k_wprep(const float* __restrict__ Wl0, const float* __restrict__ Wr0,
                        const float* __restrict__ Wl1, const float* __restrict__ Wr1,
                        const float* __restrict__ Wl2, const float* __restrict__ Wr2,
                        u16* __restrict__ W1t, u16* __restrict__ W2t, u16* __restrict__ W3t){
  int idx = blockIdx.x*256 + threadIdx.x;
  if (idx < 256*256){                       // W1t [256][256]: k<128 Wl0, else Wr0
    int n = idx >> 8, k = idx & 255;
    float v = (k < 128) ? Wl0[k*256 + n] : Wr0[(k-128)*256 + n];
    W1t[idx] = (u16)f2bf_bits(v);
  } else if (idx < 256*256 + 256*512){      // W2t [256][512]: k<256 Wl1, else Wr1
    int j = idx - 256*256;
    int n = j >> 9, k = j & 511;
    float v = (k < 256) ? Wl1[k*256 + n] : Wr1[(k-256)*256 + n];
    W2t[j] = (u16)f2bf_bits(v);
  } else {                                  // W3t [128][256]: n<47 Wl2, 48..94 Wr2, else 0
    int j = idx - (256*256 + 256*512);
    int n = j >> 8, k = j & 255;
    float v = 0.f;
    if (n < 47) v = Wl2[k*47 + n];
    else if (n >= 48 && n < 95) v = Wr2[k*47 + (n-48)];
    W3t[j] = (u16)f2bf_bits(v);
  }
}

__global__ void k_xconv(const float* __restrict__ x, u16* __restrict__ xb){
  int i = blockIdx.x*256 + threadIdx.x;     // 4 floats per thread
  if (i >= NN*128/4) return;
  const float4* xp = (const float4*)x;
  float4 v = xp[i];
  u32 lo = f2bf_bits(v.x) | (f2bf_bits(v.y) << 16);
  u32 hi = f2bf_bits(v.z) | (f2bf_bits(v.w) << 16);
  ((u32*)xb)[2*i]   = lo;
  ((u32*)xb)[2*i+1] = hi;
}

// ---------------- mean aggregation: 1 wave/node, wide loads, deep unroll ----------------
// EPL = F/64 bf16 per lane (2 -> dword, 4 -> dwordx2). UN-deep neighbor unroll.
template<int F, int UN>
__global__ __launch_bounds__(256) void k_agg(const u16* __restrict__ feat,
    const int* __restrict__ row_start, const int* __restrict__ cnt,
    const float* __restrict__ rdeg, const int* __restrict__ ssrc,
    u16* __restrict__ out){
  constexpr int EPL = F/64;
  int i = blockIdx.x*4 + (threadIdx.x >> 6);
  if (i >= NN) return;
  int lane = threadIdx.x & 63;
  const u16* fp = feat + (size_t)lane*EPL;
  int beg = row_start[i], num = cnt[i];
  float a0=0.f, b0=0.f, a1=0.f, b1=0.f;
  int j = 0;
  for (; j + UN <= num; j += UN){
    u32 w0[UN], w1[UN];
    #pragma unroll
    for (int u = 0; u < UN; u++){
      const u16* q = fp + (size_t)ssrc[beg+j+u]*F;
      if constexpr (EPL == 4){ uint2 t2 = *(const uint2*)q; w0[u] = t2.x; w1[u] = t2.y; }
      else                   { w0[u] = *(const u32*)q; }
    }
    #pragma unroll
    for (int u = 0; u < UN; u++){
      a0 += __uint_as_float(w0[u] << 16); b0 += __uint_as_float(w0[u] & 0xffff0000u);
      if constexpr (EPL == 4){
        a1 += __uint_as_float(w1[u] << 16); b1 += __uint_as_float(w1[u] & 0xffff0000u);
      }
    }
  }
  for (; j + 2 <= num; j += 2){              // 2-deep tail (LOOP — handles any remainder)
    u32 w0[2], w1[2];
    #pragma unroll
    for (int u = 0; u < 2; u++){
      const u16* q = fp + (size_t)ssrc[beg+j+u]*F;
      if constexpr (EPL == 4){ uint2 t2 = *(const uint2*)q; w0[u] = t2.x; w1[u] = t2.y; }
      else                   { w0[u] = *(const u32*)q; }
    }
    #pragma unroll
    for (int u = 0; u < 2; u++){
      a0 += __uint_as_float(w0[u] << 16); b0 += __uint_as_float(w0[u] & 0xffff0000u);
      if constexpr (EPL == 4){
        a1 += __uint_as_float(w1[u] << 16); b1 += __uint_as_float(w1[u] & 0xffff0000u);
      }
    }
  }
  if (j < num){                              // 1 tail
    const u16* q = fp + (size_t)ssrc[beg+j]*F;
    if constexpr (EPL == 4){
      uint2 t2 = *(const uint2*)q;
      a0 += __uint_as_float(t2.x << 16); b0 += __uint_as_float(t2.x & 0xffff0000u);
      a1 += __uint_as_float(t2.y << 16); b1 += __uint_as_float(t2.y & 0xffff0000u);
    } else {
      u32 p = *(const u32*)q;
      a0 += __uint_as_float(p << 16); b0 += __uint_as_float(p & 0xffff0000u);
    }
  }
  float r = rdeg[i];
  if constexpr (EPL == 4){
    uint2 pk;
    pk.x = f2bf_bits(a0*r) | (f2bf_bits(b0*r) << 16);
    pk.y = f2bf_bits(a1*r) | (f2bf_bits(b1*r) << 16);
    *(uint2*)(out + (size_t)i*F + lane*4) = pk;
  } else {
    *(u32*)(out + (size_t)i*F + lane*2) = f2bf_bits(a0*r) | (f2bf_bits(b0*r) << 16);
  }
}

// ---------------- bf16 MFMA GEMM, 128x128 tile, BK=64, dual-A (K-concat) ----------------
template<bool RELU>
__global__ __launch_bounds__(256) void k_gemm(
    const u16* __restrict__ A1, int K1, const u16* __restrict__ A2, int K2,
    const u16* __restrict__ Bt, const float* __restrict__ bias,
    u16* __restrict__ C, int ldc){
  __shared__ u16 As[128*64];
  __shared__ u16 Bs[128*64];
  const int M = NN;
  const int K = K1 + K2;
  const int gm = (M + 127) >> 7;
  int bm = blockIdx.x % gm, bn = blockIdx.x / gm;
  int tid = threadIdx.x;
  int lane = tid & 63, w = tid >> 6;
  int wm = w >> 1, wn = w & 1;               // 4 waves = 2x2, 64x64 each
  int lr = lane & 15, l4 = lane >> 4;
  f32x4 acc[4][4] = {};
  const int nk = K >> 6;
  for (int kstep = 0; kstep < nk; kstep++){
    __syncthreads();
    #pragma unroll
    for (int q = 0; q < 4; q++){
      int L = q*4096 + tid*16;                // linear LDS dest (gload_lds requirement)
      int row = L >> 7;                       // 128B per row (64 bf16)
      int c16 = ((L >> 4) & 7) ^ (row & 7);   // inverse-swizzled SOURCE
      int gk = (kstep << 6) + (c16 << 3);
      int grow = bm*128 + row; if (grow >= M) grow = M - 1;
      const u16* ga = (gk < K1) ? (A1 + (size_t)grow*K1 + gk)
                                : (A2 + (size_t)grow*K2 + (gk - K1));
      gload16(ga, (char*)As + L);
      int gcol = bn*128 + row;
      gload16(Bt + (size_t)gcol*K + gk, (char*)Bs + L);
    }
    __syncthreads();
    #pragma unroll
    for (int kk = 0; kk < 2; kk++){
      bf16x8 af[4], bf[4];
      #pragma unroll
      for (int fm = 0; fm < 4; fm++){
        int row = wm*64 + fm*16 + lr;
        int c16 = (kk << 2) + l4;
        af[fm] = *(const bf16x8*)((const char*)As + row*128 + ((c16 ^ (row&7)) << 4));
      }
      #pragma unroll
      for (int fn = 0; fn < 4; fn++){
        int row = wn*64 + fn*16 + lr;
        int c16 = (kk << 2) + l4;
        bf[fn] = *(const bf16x8*)((const char*)Bs + row*128 + ((c16 ^ (row&7)) << 4));
      }
      #pragma unroll
      for (int fm = 0; fm < 4; fm++)
        #pragma unroll
        for (int fn = 0; fn < 4; fn++)
          acc[fm][fn] = __builtin_amdgcn_mfma_f32_16x16x32_bf16(af[fm], bf[fn], acc[fm][fn], 0, 0, 0);
    }
  }
  #pragma unroll
  for (int fn = 0; fn < 4; fn++){
    int col = bn*128 + wn*64 + fn*16 + lr;
    float bv = bias ? bias[col] : 0.f;
    #pragma unroll
    for (int fm = 0; fm < 4; fm++){
      #pragma unroll
      for (int q = 0; q < 4; q++){
        int rowg = bm*128 + wm*64 + fm*16 + l4*4 + q;
        if (rowg < M){
          float v = acc[fm][fn][q] + bv;
          if (RELU) v = fmaxf(v, 0.f);
          C[(size_t)rowg*ldc + col] = (u16)f2bf_bits(v);
        }
      }
    }
  }
}

// ---------------- layer3 tail: agg(t) + root + b2 + log_softmax ----------------
// half-wave (32 lanes) per node; lane t owns features 2t, 2t+1 (valid < 47)
__global__ __launch_bounds__(256) void k_final(const u16* __restrict__ G,
    const int* __restrict__ row_start, const int* __restrict__ cnt,
    const float* __restrict__ rdeg, const int* __restrict__ ssrc,
    const float* __restrict__ b2, float* __restrict__ out){
  int i = blockIdx.x*8 + (threadIdx.x >> 5);
  if (i >= NN) return;
  int t = threadIdx.x & 31;
  int beg = row_start[i], num = cnt[i];
  const u16* gp = G + 2*t;                   // cols 2t, 2t+1 (<=63, in-bounds)
  float a = 0.f, b = 0.f;
  int j = 0;
  for (; j + 4 <= num; j += 4){
    u32 w[4];
    #pragma unroll
    for (int u = 0; u < 4; u++) w[u] = *(const u32*)(gp + (size_t)ssrc[beg+j+u]*128);
    #pragma unroll
    for (int u = 0; u < 4; u++){ a += __uint_as_float(w[u] << 16); b += __uint_as_float(w[u] & 0xffff0000u); }
  }
  for (; j < num; j++){
    u32 w = *(const u32*)(gp + (size_t)ssrc[beg+j]*128);
    a += __uint_as_float(w << 16); b += __uint_as_float(w & 0xffff0000u);
  }
  float r = rdeg[i];
  u32 rw = *(const u32*)(G + (size_t)i*128 + 48 + 2*t);  // root cols 48+2t, 49+2t
  int f0 = 2*t, f1 = 2*t + 1;
  float va = (f0 < 47) ? a*r + __uint_as_float(rw << 16)          + b2[f0] : -3.0e38f;
  float vb = (f1 < 47) ? b*r + __uint_as_float(rw & 0xffff0000u)  + b2[f1] : -3.0e38f;
  float m = fmaxf(va, vb);
  #pragma unroll
  for (int o = 16; o > 0; o >>= 1) m = fmaxf(m, __shfl_xor(m, o, 32));
  float e = 0.f;
  if (f0 < 47) e += expf(va - m);
  if (f1 < 47) e += expf(vb - m);
  float s = e;
  #pragma unroll
  for (int o = 16; o > 0; o >>= 1) s += __shfl_xor(s, o, 32);
  float ls = logf(s);
  if (f0 < 47) out[(size_t)i*47 + f0] = va - m - ls;
  if (f1 < 47) out[(size_t)i*47 + f1] = vb - m - ls;
}

// ---------------- launcher ----------------
extern "C" void kernel_launch(void* const* d_in, const int* in_sizes, int n_in,
                              void* d_out, int out_size, void* d_ws, size_t ws_size,
                              hipStream_t stream){
  const float* x   = (const float*)d_in[0];
  const int*   src = (const int*)d_in[1];
  const int*   dst = (const int*)d_in[2];
  const float* Wl0 = (const float*)d_in[3];
  const float* Wr0 = (const float*)d_in[4];
  const float* b0  = (const float*)d_in[5];
  const float* Wl1 = (const float*)d_in[6];
  const float* Wr1 = (const float*)d_in[7];
  const float* b1  = (const float*)d_in[8];
  const float* Wl2 = (const float*)d_in[9];
  const float* Wr2 = (const float*)d_in[10];
  const float* b2  = (const float*)d_in[11];
  float* out = (float*)d_out;

  char* p = (char*)d_ws;
  size_t off = 0;
  auto alloc = [&](size_t bytes)->char*{
    char* r = p + off; off += (bytes + 511) & ~((size_t)511); return r;
  };
  int*   cnt       = (int*)  alloc((size_t)NN*4);
  int*   row_start = (int*)  alloc((size_t)NN*4);
  int*   fill_ptr  = (int*)  alloc((size_t)NN*4);
  float* rdeg      = (float*)alloc((size_t)NN*4);
  int*   bsum      = (int*)  alloc(512);
  int*   ssrc      = (int*)  alloc((size_t)NE*4);
  u16*   W1t       = (u16*)  alloc((size_t)256*256*2);
  u16*   W2t       = (u16*)  alloc((size_t)256*512*2);
  u16*   W3t       = (u16*)  alloc((size_t)128*256*2);
  u16*   xb        = (u16*)  alloc((size_t)NN*128*2);  // reused as G after GEMM3
  u16*   agg1      = (u16*)  alloc((size_t)NN*128*2);
  u16*   h1        = (u16*)  alloc((size_t)NN*256*2);
  u16*   agg2      = (u16*)  alloc((size_t)NN*256*2);
  u16*   h2        = (u16*)  alloc((size_t)NN*256*2);
  u16*   G = xb;

  const int nb_scan = (NN + 1023) / 1024;

  hipMemsetAsync(cnt, 0, (size_t)NN*4, stream);
  k_hist <<<NE/256, 256, 0, stream>>>(dst, cnt);
  k_scan1<<<nb_scan, 1024, 0, stream>>>(cnt, row_start, bsum);
  k_scan2<<<1, 64, 0, stream>>>(bsum, nb_scan);
  k_scan3<<<(NN+255)/256, 256, 0, stream>>>(cnt, row_start, bsum, fill_ptr, rdeg);
  k_fill <<<8*784, 256, 0, stream>>>(src, dst, fill_ptr, ssrc);
  k_wprep<<<(256*256 + 256*512 + 128*256)/256, 256, 0, stream>>>(Wl0,Wr0,Wl1,Wr1,Wl2,Wr2,W1t,W2t,W3t);
  k_xconv<<<(NN*128/4 + 255)/256, 256, 0, stream>>>(x, xb);

  // layer 1: agg(x) 128-dim, then h1 = relu([agg1|x] @ W1t + b0)
  k_agg<128,16><<<(NN+3)/4, 256, 0, stream>>>(xb, row_start, cnt, rdeg, ssrc, agg1);
  k_gemm<true><<<782*2, 256, 0, stream>>>(agg1, 128, xb, 128, W1t, b0, h1, 256);

  // layer 2: agg(h1) 256-dim, then h2 = relu([agg2|h1] @ W2t + b1)
  k_agg<256,8><<<(NN+3)/4, 256, 0, stream>>>(h1, row_start, cnt, rdeg, ssrc, agg2);
  k_gemm<true><<<782*2, 256, 0, stream>>>(agg2, 256, h1, 256, W2t, b1, h2, 256);

  // layer 3: G = h2 @ [Wl2|Wr2] (N padded to 128), then agg(t)+root+b2+log_softmax
  k_gemm<false><<<782, 256, 0, stream>>>(h2, 256, h2, 0, W3t, nullptr, G, 128);
  k_final<<<(NN+7)/8, 256, 0, stream>>>(G, row_start, cnt, rdeg, ssrc, b2, out);
}

// Round 8
// 653.711 us; speedup vs baseline: 1.2983x; 1.0236x over previous
//
#include <hip/hip_runtime.h>
#include <stdint.h>

typedef unsigned int u32;
typedef unsigned short u16;

typedef __attribute__((ext_vector_type(4))) float f32x4;
typedef __attribute__((ext_vector_type(8))) __bf16 bf16x8;

#define NN 100000
#define NE 1600000
#define NSLICE 8
#define SLICE_NODES 12500   // NN / NSLICE exactly

typedef __attribute__((address_space(1))) u32 ga_u32;
typedef __attribute__((address_space(3))) u32 ls_u32;

static __device__ __forceinline__ u32 f2bf_bits(float f){
  u32 u = __float_as_uint(f);
  return (u + 0x7fffu + ((u >> 16) & 1u)) >> 16;   // RNE f32->bf16
}
static __device__ __forceinline__ float bf2f(u16 h){ return __uint_as_float(((u32)h) << 16); }

static __device__ __forceinline__ void gload16(const void* g, void* l){
  __builtin_amdgcn_global_load_lds((const ga_u32*)g, (ls_u32*)l, 16, 0, 0);
}

// ---------------- CSR build (counting sort by dst) ----------------
__global__ void k_hist(const int* __restrict__ dst, int* __restrict__ cnt){
  int e = blockIdx.x*256 + threadIdx.x;
  if (e < NE) atomicAdd(&cnt[dst[e]], 1);
}

__global__ void k_scan1(const int* __restrict__ cnt, int* __restrict__ excl, int* __restrict__ bsum){
  __shared__ int s[1024];
  int t = threadIdx.x;
  int i = blockIdx.x*1024 + t;
  int v = (i < NN) ? cnt[i] : 0;
  s[t] = v; __syncthreads();
  int acc = v;
  for (int off = 1; off < 1024; off <<= 1){
    int tmp = (t >= off) ? s[t-off] : 0;
    __syncthreads();
    acc += tmp; s[t] = acc;
    __syncthreads();
  }
  if (i < NN) excl[i] = acc - v;           // block-local exclusive
  if (t == 1023) bsum[blockIdx.x] = acc;   // block total
}

__global__ void k_scan2(int* bsum, int nb){
  if (threadIdx.x == 0 && blockIdx.x == 0){
    int run = 0;
    for (int b = 0; b < nb; b++){ int t = bsum[b]; bsum[b] = run; run += t; }
  }
}

__global__ void k_scan3(const int* __restrict__ cnt, int* __restrict__ row_start,
                        const int* __restrict__ bsum, int* __restrict__ fill_ptr,
                        float* __restrict__ rdeg){
  int i = blockIdx.x*256 + threadIdx.x;
  if (i >= NN) return;
  int rs = row_start[i] + bsum[i >> 10];
  row_start[i] = rs;
  fill_ptr[i]  = rs;
  int c = cnt[i];
  rdeg[i] = 1.0f / (float)(c > 1 ? c : 1);
}

// dst-sliced fill: slice = blockIdx&7 -> one XCD's L2 owns each slice's lines.
__global__ __launch_bounds__(256) void k_fill(const int* __restrict__ src,
    const int* __restrict__ dst, int* __restrict__ fill_ptr, int* __restrict__ ssrc){
  int slice = blockIdx.x & 7;
  int bin   = blockIdx.x >> 3;
  int nbin  = gridDim.x >> 3;
  int lo = slice * SLICE_NODES;
  int hi = lo + SLICE_NODES;
  for (int e = bin*256 + threadIdx.x; e < NE; e += nbin*256){
    int d = dst[e];
    if (d >= lo && d < hi){
      int pos = atomicAdd(&fill_ptr[d], 1);
      ssrc[pos] = src[e];
    }
  }
}

// ---------------- weight prep: transpose to [N][K] bf16, K-concat [Wl;Wr] ----------------
__global__ void k_wprep(const float* __restrict__ Wl0, const float* __restrict__ Wr0,
                        const float* __restrict__ Wl1, const float* __restrict__ Wr1,
                        const float* __restrict__ Wl2, const float* __restrict__ Wr2,
                        u16* __restrict__ W1t, u16* __restrict__ W2t, u16* __restrict__ W3t){
  int idx = blockIdx.x*256 + threadIdx.x;
  if (idx < 256*256){                       // W1t [256][256]: k<128 Wl0, else Wr0
    int n = idx >> 8, k = idx & 255;
    float v = (k < 128) ? Wl0[k*256 + n] : Wr0[(k-128)*256 + n];
    W1t[idx] = (u16)f2bf_bits(v);
  } else if (idx < 256*256 + 256*512){      // W2t [256][512]: k<256 Wl1, else Wr1
    int j = idx - 256*256;
    int n = j >> 9, k = j & 511;
    float v = (k < 256) ? Wl1[k*256 + n] : Wr1[(k-256)*256 + n];
    W2t[j] = (u16)f2bf_bits(v);
  } else {                                  // W3t [128][256]: n<47 Wl2 (->Gl), n 64..110 Wr2 (->Gr)
    int j = idx - (256*256 + 256*512);
    int n = j >> 8, k = j & 255;
    float v = 0.f;
    if (n < 47) v = Wl2[k*47 + n];
    else if (n >= 64 && n < 111) v = Wr2[k*47 + (n-64)];
    W3t[j] = (u16)f2bf_bits(v);
  }
}

__global__ void k_xconv(const float* __restrict__ x, u16* __restrict__ xb){
  int i = blockIdx.x*256 + threadIdx.x;     // 4 floats per thread
  if (i >= NN*128/4) return;
  const float4* xp = (const float4*)x;
  float4 v = xp[i];
  u32 lo = f2bf_bits(v.x) | (f2bf_bits(v.y) << 16);
  u32 hi = f2bf_bits(v.z) | (f2bf_bits(v.w) << 16);
  ((u32*)xb)[2*i]   = lo;
  ((u32*)xb)[2*i+1] = hi;
}

// ---------------- mean aggregation: 1 wave/node, dwordx4 loads, multi-row per instr ----
// Each 16B lane-load covers 8 bf16; LPR = F/8 lanes per row; G = 64/LPR rows per
// load instruction (F=256 -> 2, F=128 -> 4). UN-deep supersteps. Wave-uniform flow.
static __device__ __forceinline__ void acc8(float* a, uint4 w){
  a[0] += __uint_as_float(w.x << 16); a[1] += __uint_as_float(w.x & 0xffff0000u);
  a[2] += __uint_as_float(w.y << 16); a[3] += __uint_as_float(w.y & 0xffff0000u);
  a[4] += __uint_as_float(w.z << 16); a[5] += __uint_as_float(w.z & 0xffff0000u);
  a[6] += __uint_as_float(w.w << 16); a[7] += __uint_as_float(w.w & 0xffff0000u);
}

template<int F, int UN>
__global__ __launch_bounds__(256) void k_agg(const u16* __restrict__ feat,
    const int* __restrict__ row_start, const int* __restrict__ cnt,
    const float* __restrict__ rdeg, const int* __restrict__ ssrc,
    u16* __restrict__ out){
  constexpr int LPR = F/8;        // lanes per row
  constexpr int G   = 64/LPR;     // rows per load instr
  int i = blockIdx.x*4 + (threadIdx.x >> 6);
  if (i >= NN) return;
  int lane = threadIdx.x & 63;
  int lir  = lane & (LPR-1);
  int sub  = lane >> (F == 256 ? 5 : 4);   // 0..G-1
  const u16* base = feat + lir*8;
  int beg = row_start[i], num = cnt[i];
  float a[8] = {0.f,0.f,0.f,0.f,0.f,0.f,0.f,0.f};
  int j = 0;
  for (; j + G*UN <= num; j += G*UN){       // UN loads in flight (16B each)
    uint4 w[UN];
    #pragma unroll
    for (int u = 0; u < UN; u++)
      w[u] = *(const uint4*)(base + (size_t)ssrc[beg + j + u*G + sub]*F);
    #pragma unroll
    for (int u = 0; u < UN; u++) acc8(a, w[u]);
  }
  for (; j + G <= num; j += G){             // G-row tail
    uint4 w = *(const uint4*)(base + (size_t)ssrc[beg + j + sub]*F);
    acc8(a, w);
  }
  int rem = num - j;                        // 0..G-1 leftover rows
  if (rem > 0){
    int idx = ssrc[beg + j + (sub < rem ? sub : 0)];
    uint4 w = *(const uint4*)(base + (size_t)idx*F);
    if (sub < rem) acc8(a, w);
  }
  #pragma unroll
  for (int k = 0; k < 8; k++)
    for (int off = LPR; off < 64; off <<= 1)
      a[k] += __shfl_xor(a[k], off, 64);
  if (sub == 0){
    float r = rdeg[i];
    uint4 pk;
    pk.x = f2bf_bits(a[0]*r) | (f2bf_bits(a[1]*r) << 16);
    pk.y = f2bf_bits(a[2]*r) | (f2bf_bits(a[3]*r) << 16);
    pk.z = f2bf_bits(a[4]*r) | (f2bf_bits(a[5]*r) << 16);
    pk.w = f2bf_bits(a[6]*r) | (f2bf_bits(a[7]*r) << 16);
    *(uint4*)(out + (size_t)i*F + lir*8) = pk;
  }
}

// ---------------- bf16 MFMA GEMM, 128x128 tile, BK=64, dual-A (K-concat) ----------------
// If C2 != nullptr: split write, cols 0..63 -> C (ldc 64), cols 64..127 -> C2 (ldc 64).
template<bool RELU>
__global__ __launch_bounds__(256) void k_gemm(
    const u16* __restrict__ A1, int K1, const u16* __restrict__ A2, int K2,
    const u16* __restrict__ Bt, const float* __restrict__ bias,
    u16* __restrict__ C, int ldc, u16* __restrict__ C2){
  __shared__ u16 As[128*64];
  __shared__ u16 Bs[128*64];
  const int M = NN;
  const int K = K1 + K2;
  const int gm = (M + 127) >> 7;
  int bm = blockIdx.x % gm, bn = blockIdx.x / gm;
  int tid = threadIdx.x;
  int lane = tid & 63, w = tid >> 6;
  int wm = w >> 1, wn = w & 1;               // 4 waves = 2x2, 64x64 each
  int lr = lane & 15, l4 = lane >> 4;
  f32x4 acc[4][4] = {};
  const int nk = K >> 6;
  for (int kstep = 0; kstep < nk; kstep++){
    __syncthreads();
    #pragma unroll
    for (int q = 0; q < 4; q++){
      int L = q*4096 + tid*16;                // linear LDS dest (gload_lds requirement)
      int row = L >> 7;                       // 128B per row (64 bf16)
      int c16 = ((L >> 4) & 7) ^ (row & 7);   // inverse-swizzled SOURCE
      int gk = (kstep << 6) + (c16 << 3);
      int grow = bm*128 + row; if (grow >= M) grow = M - 1;
      const u16* ga = (gk < K1) ? (A1 + (size_t)grow*K1 + gk)
                                : (A2 + (size_t)grow*K2 + (gk - K1));
      gload16(ga, (char*)As + L);
      int gcol = bn*128 + row;
      gload16(Bt + (size_t)gcol*K + gk, (char*)Bs + L);
    }
    __syncthreads();
    #pragma unroll
    for (int kk = 0; kk < 2; kk++){
      bf16x8 af[4], bf[4];
      #pragma unroll
      for (int fm = 0; fm < 4; fm++){
        int row = wm*64 + fm*16 + lr;
        int c16 = (kk << 2) + l4;
        af[fm] = *(const bf16x8*)((const char*)As + row*128 + ((c16 ^ (row&7)) << 4));
      }
      #pragma unroll
      for (int fn = 0; fn < 4; fn++){
        int row = wn*64 + fn*16 + lr;
        int c16 = (kk << 2) + l4;
        bf[fn] = *(const bf16x8*)((const char*)Bs + row*128 + ((c16 ^ (row&7)) << 4));
      }
      #pragma unroll
      for (int fm = 0; fm < 4; fm++)
        #pragma unroll
        for (int fn = 0; fn < 4; fn++)
          acc[fm][fn] = __builtin_amdgcn_mfma_f32_16x16x32_bf16(af[fm], bf[fn], acc[fm][fn], 0, 0, 0);
    }
  }
  #pragma unroll
  for (int fn = 0; fn < 4; fn++){
    int col = bn*128 + wn*64 + fn*16 + lr;
    float bv = bias ? bias[col] : 0.f;
    #pragma unroll
    for (int fm = 0; fm < 4; fm++){
      #pragma unroll
      for (int q = 0; q < 4; q++){
        int rowg = bm*128 + wm*64 + fm*16 + l4*4 + q;
        if (rowg < M){
          float v = acc[fm][fn][q] + bv;
          if (RELU) v = fmaxf(v, 0.f);
          u16* cp;
          if (C2 == nullptr) cp = C + (size_t)rowg*ldc + col;
          else cp = (col < 64) ? C  + (size_t)rowg*64 + col
                               : C2 + (size_t)rowg*64 + (col - 64);
          *cp = (u16)f2bf_bits(v);
        }
      }
    }
  }
}

// ---------------- layer3 tail: agg(Gl) + Gr(root) + b2 + log_softmax ----------------
// half-wave (32 lanes) per node; lane t owns features 2t, 2t+1 (valid < 47)
// Gl rows are 64 u16 (128B) -> 12.8 MB gather working set (L2-resident).
__global__ __launch_bounds__(256) void k_final(const u16* __restrict__ Gl,
    const u16* __restrict__ Gr, const int* __restrict__ row_start,
    const int* __restrict__ cnt, const float* __restrict__ rdeg,
    const int* __restrict__ ssrc, const float* __restrict__ b2,
    float* __restrict__ out){
  int i = blockIdx.x*8 + (threadIdx.x >> 5);
  if (i >= NN) return;
  int t = threadIdx.x & 31;
  int beg = row_start[i], num = cnt[i];
  const u16* gp = Gl + 2*t;                  // cols 2t, 2t+1 (<=63, in-bounds)
  float a = 0.f, b = 0.f;
  int j = 0;
  for (; j + 4 <= num; j += 4){
    u32 w[4];
    #pragma unroll
    for (int u = 0; u < 4; u++) w[u] = *(const u32*)(gp + (size_t)ssrc[beg+j+u]*64);
    #pragma unroll
    for (int u = 0; u < 4; u++){ a += __uint_as_float(w[u] << 16); b += __uint_as_float(w[u] & 0xffff0000u); }
  }
  for (; j < num; j++){
    u32 w = *(const u32*)(gp + (size_t)ssrc[beg+j]*64);
    a += __uint_as_float(w << 16); b += __uint_as_float(w & 0xffff0000u);
  }
  float r = rdeg[i];
  u32 rw = *(const u32*)(Gr + (size_t)i*64 + 2*t);  // root cols 2t, 2t+1
  int f0 = 2*t, f1 = 2*t + 1;
  float va = (f0 < 47) ? a*r + __uint_as_float(rw << 16)          + b2[f0] : -3.0e38f;
  float vb = (f1 < 47) ? b*r + __uint_as_float(rw & 0xffff0000u)  + b2[f1] : -3.0e38f;
  float m = fmaxf(va, vb);
  #pragma unroll
  for (int o = 16; o > 0; o >>= 1) m = fmaxf(m, __shfl_xor(m, o, 32));
  float e = 0.f;
  if (f0 < 47) e += expf(va - m);
  if (f1 < 47) e += expf(vb - m);
  float s = e;
  #pragma unroll
  for (int o = 16; o > 0; o >>= 1) s += __shfl_xor(s, o, 32);
  float ls = logf(s);
  if (f0 < 47) out[(size_t)i*47 + f0] = va - m - ls;
  if (f1 < 47) out[(size_t)i*47 + f1] = vb - m - ls;
}

// ---------------- launcher ----------------
extern "C" void kernel_launch(void* const* d_in, const int* in_sizes, int n_in,
                              void* d_out, int out_size, void* d_ws, size_t ws_size,
                              hipStream_t stream){
  const float* x   = (const float*)d_in[0];
  const int*   src = (const int*)d_in[1];
  const int*   dst = (const int*)d_in[2];
  const float* Wl0 = (const float*)d_in[3];
  const float* Wr0 = (const float*)d_in[4];
  const float* b0  = (const float*)d_in[5];
  const float* Wl1 = (const float*)d_in[6];
  const float* Wr1 = (const float*)d_in[7];
  const float* b1  = (const float*)d_in[8];
  const float* Wl2 = (const float*)d_in[9];
  const float* Wr2 = (const float*)d_in[10];
  const float* b2  = (const float*)d_in[11];
  float* out = (float*)d_out;

  char* p = (char*)d_ws;
  size_t off = 0;
  auto alloc = [&](size_t bytes)->char*{
    char* r = p + off; off += (bytes + 511) & ~((size_t)511); return r;
  };
  int*   cnt       = (int*)  alloc((size_t)NN*4);
  int*   row_start = (int*)  alloc((size_t)NN*4);
  int*   fill_ptr  = (int*)  alloc((size_t)NN*4);
  float* rdeg      = (float*)alloc((size_t)NN*4);
  int*   bsum      = (int*)  alloc(512);
  int*   ssrc      = (int*)  alloc((size_t)NE*4);
  u16*   W1t       = (u16*)  alloc((size_t)256*256*2);
  u16*   W2t       = (u16*)  alloc((size_t)256*512*2);
  u16*   W3t       = (u16*)  alloc((size_t)128*256*2);
  u16*   xb        = (u16*)  alloc((size_t)NN*128*2);  // reused as Gl|Gr after GEMM3
  u16*   agg1      = (u16*)  alloc((size_t)NN*128*2);
  u16*   h1        = (u16*)  alloc((size_t)NN*256*2);
  u16*   agg2      = (u16*)  alloc((size_t)NN*256*2);
  u16*   h2        = (u16*)  alloc((size_t)NN*256*2);
  u16*   Gl = xb;
  u16*   Gr = xb + (size_t)NN*64;

  const int nb_scan = (NN + 1023) / 1024;

  hipMemsetAsync(cnt, 0, (size_t)NN*4, stream);
  k_hist <<<NE/256, 256, 0, stream>>>(dst, cnt);
  k_scan1<<<nb_scan, 1024, 0, stream>>>(cnt, row_start, bsum);
  k_scan2<<<1, 64, 0, stream>>>(bsum, nb_scan);
  k_scan3<<<(NN+255)/256, 256, 0, stream>>>(cnt, row_start, bsum, fill_ptr, rdeg);
  k_fill <<<8*784, 256, 0, stream>>>(src, dst, fill_ptr, ssrc);
  k_wprep<<<(256*256 + 256*512 + 128*256)/256, 256, 0, stream>>>(Wl0,Wr0,Wl1,Wr1,Wl2,Wr2,W1t,W2t,W3t);
  k_xconv<<<(NN*128/4 + 255)/256, 256, 0, stream>>>(x, xb);

  // layer 1: agg(x) 128-dim, then h1 = relu([agg1|x] @ W1t + b0)
  k_agg<128,4><<<(NN+3)/4, 256, 0, stream>>>(xb, row_start, cnt, rdeg, ssrc, agg1);
  k_gemm<true><<<782*2, 256, 0, stream>>>(agg1, 128, xb, 128, W1t, b0, h1, 256, nullptr);

  // layer 2: agg(h1) 256-dim, then h2 = relu([agg2|h1] @ W2t + b1)
  k_agg<256,6><<<(NN+3)/4, 256, 0, stream>>>(h1, row_start, cnt, rdeg, ssrc, agg2);
  k_gemm<true><<<782*2, 256, 0, stream>>>(agg2, 256, h1, 256, W2t, b1, h2, 256, nullptr);

  // layer 3: [Gl|Gr] = h2 @ [Wl2|pad|Wr2] (split write), then agg+root+b2+log_softmax
  k_gemm<false><<<782, 256, 0, stream>>>(h2, 256, h2, 0, W3t, nullptr, Gl, 64, Gr);
  k_final<<<(NN+7)/8, 256, 0, stream>>>(Gl, Gr, row_start, cnt, rdeg, ssrc, b2, out);
}